// Round 31
// baseline (227.935 us; speedup 1.0000x reference)
//
#include <hip/hip_runtime.h>
#include <hip/hip_bf16.h>

#define BB 16
#define CIN 256
#define DD 256
#define HH 96
#define NPIX 9216
#define HEADS 8
#define HD 32
#define MM 4
#define NT 144

typedef short bf16x8 __attribute__((ext_vector_type(8)));
typedef float f32x4 __attribute__((ext_vector_type(4)));

__device__ __forceinline__ float b2f(unsigned u) {
    unsigned x = u << 16;
    return __builtin_bit_cast(float, x);
}
__device__ __forceinline__ ushort f2b(float f) {
    unsigned x = __builtin_bit_cast(unsigned, f);
    unsigned r = (x + 0x7FFF + ((x >> 16) & 1)) >> 16;  // RNE
    return (ushort)r;
}
__device__ __forceinline__ unsigned cvtpk(float lo, float hi) {
    unsigned r;
    asm("v_cvt_pk_bf16_f32 %0, %1, %2" : "=v"(r) : "v"(lo), "v"(hi));
    return r;   // {bf16(hi)<<16 | bf16(lo)}, RNE — bit-identical to f2b pair
}

// ---------------------------------------------------------------------------
// wprep: blocks 0..127: Wf,Wv f32 -> bf16 wb in MFMA-FRAGMENT layout:
//   chunk (g*8+kk)*4+w (2048 ushorts): [(i*64+lane)*8+j] =
//   bf16(W_g[(w*64+i*16+(lane&15))*256 + kk*32+(lane>>4)*8+j])
// blocks 128..159: GT + gb (unchanged).
// ---------------------------------------------------------------------------
__global__ __launch_bounds__(256) void wprep_kernel(const float* __restrict__ Wf,
                                                    const float* __restrict__ Wv,
                                                    const float* __restrict__ bfp,
                                                    const float* __restrict__ centers,
                                                    ushort* __restrict__ wb,
                                                    float* __restrict__ GT,
                                                    float* __restrict__ gb) {
    __shared__ float cns[4][32];
    int t = threadIdx.x;
    if (blockIdx.x < 128) {
        int idx = (blockIdx.x * 256 + t) * 4;     // linear (g, rr, k0)
        float4 v;
        if (idx < 65536) v = *(const float4*)(Wf + idx);
        else v = *(const float4*)(Wv + (idx - 65536));
        int g = idx >> 16;
        int rem = idx & 65535;
        int rr = rem >> 8, k0 = rem & 255;
        int w = rr >> 6, i = (rr >> 4) & 3, l15v = rr & 15;
        int kk = k0 >> 5, lane4 = ((k0 >> 3) & 3) * 16 + l15v, j = k0 & 7;
        size_t dst = ((size_t)((g * 8 + kk) * 4 + w)) * 2048 + (i * 64 + lane4) * 8 + j;
        ushort4 o;
        o.x = f2b(v.x); o.y = f2b(v.y); o.z = f2b(v.z); o.w = f2b(v.w);
        *(ushort4*)(wb + dst) = o;
        return;
    }
    if (t < 4) {
        float c[32]; float s = 0.f;
        for (int d = 0; d < 32; ++d) { c[d] = centers[t * 32 + d]; s += c[d] * c[d]; }
        float inv = 1.f / fmaxf(sqrtf(s), 1e-12f);
        for (int d = 0; d < 32; ++d) cns[t][d] = c[d] * inv;
    }
    __syncthreads();
    int i = (blockIdx.x - 128) * 256 + t;
    int c = i >> 5, em = i & 31;
    int e = em >> 2, m = em & 3;
    float s = 0.f;
#pragma unroll 8
    for (int d = 0; d < 32; ++d) s += cns[m][d] * Wf[(e * 32 + d) * 256 + c];
    GT[i] = s;
    if (blockIdx.x == 128 && t < 32) {
        int e2 = t >> 2, m2 = t & 3;
        float sb = 0.f;
        for (int d = 0; d < 32; ++d) sb += cns[m2][d] * bfp[e2 * 32 + d];
        gb[t] = sb;
    }
}

// ---------------------------------------------------------------------------
// gmap v8: single x pass. Block = 64 n x all 32 em; x tile staged in LDS
// (64 KB, [c][n], 2-way banks both phases). Wave w computes em in
// [w*8, w*8+8) (heads 2w, 2w+1) for lane's pixel n. GT base uses
// readfirstlane(t>>6) -> SGPR -> s_load path preserved (r24-proven).
// Per-em FMA order ascending c from gb[em] -> bitwise-identical outputs.
// Grid (144, 16).
// ---------------------------------------------------------------------------
__global__ __launch_bounds__(256) void gmap_kernel(const float* __restrict__ x,
                                                   const float* __restrict__ GT,
                                                   const float* __restrict__ gb,
                                                   const float* __restrict__ alpha_p,
                                                   unsigned char* __restrict__ idxg,
                                                   float* __restrict__ zbest,
                                                   float* __restrict__ mapo) {
    __shared__ float xs[256][64];   // 64 KB: [c][n]
    int b = blockIdx.y;
    int n0 = blockIdx.x * 64;
    int t = threadIdx.x;
    int lane = t & 63;
    int w = __builtin_amdgcn_readfirstlane(t >> 6);   // wave-uniform em group
    // stage: wave w loads c rows [w*64, w*64+64), lane -> n (coalesced 256B/row)
    {
        const float* xb = x + (size_t)(b * CIN + w * 64) * NPIX + n0 + lane;
#pragma unroll 8
        for (int ci = 0; ci < 64; ++ci)
            xs[w * 64 + ci][lane] = xb[(size_t)ci * NPIX];
    }
    __syncthreads();
    int em0 = w * 8;
    float acc[8];
#pragma unroll
    for (int em = 0; em < 8; ++em) acc[em] = gb[em0 + em];
    const float* gtb = GT + em0;
#pragma unroll 8
    for (int c = 0; c < 256; ++c) {
        float xv = xs[c][lane];
        const float* gr = gtb + c * 32;      // scalar base -> s_load
#pragma unroll
        for (int em = 0; em < 8; ++em) acc[em] = fmaf(gr[em], xv, acc[em]);
    }
    float alpha = alpha_p[0];
    int n = n0 + lane;
#pragma unroll
    for (int h = 0; h < 2; ++h) {
        int e = w * 2 + h;
        float z0 = alpha * acc[h * 4 + 0], z1 = alpha * acc[h * 4 + 1];
        float z2 = alpha * acc[h * 4 + 2], z3 = alpha * acc[h * 4 + 3];
        int bm = 0; float bz = z0;
        if (z1 > bz) { bz = z1; bm = 1; }
        if (z2 > bz) { bz = z2; bm = 2; }
        if (z3 > bz) { bz = z3; bm = 3; }
        size_t o = ((size_t)(b * 8 + e)) * NPIX + n;
        idxg[o] = (unsigned char)bm;
        zbest[o] = bz;
        if (b == 0 && e == 0) mapo[n] = (float)bm;
    }
}

// ---------------------------------------------------------------------------
// gemm_fvc v10: fragment-direct A loads + deferred wm (r30, verified best).
// Grid (144,16).
// ---------------------------------------------------------------------------
__global__ __launch_bounds__(256, 3) void gemm_fvc(const ushort* __restrict__ wb,
                                                   const float* __restrict__ bfp,
                                                   const float* __restrict__ bvp,
                                                   const float* __restrict__ x,
                                                   const unsigned char* __restrict__ idxg,
                                                   float* __restrict__ zsg,
                                                   const float* __restrict__ beta_p,
                                                   float* __restrict__ partial2) {
    __shared__ ushort lB[64 * 256];       // 32 KB, swizzled
    int nt = blockIdx.x, b = blockIdx.y;
    int t = threadIdx.x;
    int wave = t >> 6, lane = t & 63;
    int l15 = lane & 15, g8 = (lane >> 4) * 8, rg = lane >> 4;
    int n0 = nt * 64;

    // ---- B-stage: thread t: c-pairs c0 = s*64 + 2*(t&31), n-block (t>>5)*8
    {
        int cpl = 2 * (t & 31);
        int j0 = (t >> 5) * 8;
#pragma unroll
        for (int s = 0; s < 4; ++s) {
            int c0 = s * 64 + cpl;
            const float* xr = x + ((size_t)(b * CIN + c0)) * NPIX + n0 + j0;
            float4 u0 = *(const float4*)(xr);
            float4 u1 = *(const float4*)(xr + 4);
            float4 v0 = *(const float4*)(xr + NPIX);
            float4 v1 = *(const float4*)(xr + NPIX + 4);
            float a0[8] = {u0.x, u0.y, u0.z, u0.w, u1.x, u1.y, u1.z, u1.w};
            float a1[8] = {v0.x, v0.y, v0.z, v0.w, v1.x, v1.y, v1.z, v1.w};
#pragma unroll
            for (int i = 0; i < 8; ++i) {
                int n = j0 + i;
                int cs = c0 ^ ((n & 7) << 3);
                unsigned pk = cvtpk(a0[i], a1[i]);   // RNE, = f2b pair
                *(unsigned*)(lB + (size_t)n * 256 + cs) = pk;
            }
        }
    }

    float beta = beta_p[0];

    __syncthreads();   // lB ready (single barrier)

    // ================= Phase g=0: feat =================
    f32x4 acc[4][4] = {};
#pragma unroll
    for (int kk = 0; kk < 8; ++kk) {
        const ushort* aCh = wb + (size_t)(kk * 4 + wave) * 2048;
        int k0 = kk * 32;
        bf16x8 af[4], bb[4];
#pragma unroll
        for (int i = 0; i < 4; ++i)
            af[i] = *(const bf16x8*)(aCh + (i * 64 + lane) * 8);   // coalesced, L2-hot
#pragma unroll
        for (int j = 0; j < 4; ++j) {
            int n = j * 16 + l15;
            int cs = (k0 + g8) ^ ((n & 7) << 3);
            bb[j] = *(const bf16x8*)(lB + (size_t)n * 256 + cs);
        }
#pragma unroll
        for (int i = 0; i < 4; ++i)
#pragma unroll
            for (int j = 0; j < 4; ++j)
                acc[i][j] = __builtin_amdgcn_mfma_f32_16x16x32_bf16(af[i], bb[j], acc[i][j], 0, 0, 0);
    }
    // + feat bias (f32, unrounded)
#pragma unroll
    for (int i = 0; i < 4; ++i) {
        int cc = wave * 64 + i * 16 + rg * 4;
        float q0 = bfp[cc], q1 = bfp[cc + 1], q2 = bfp[cc + 2], q3 = bfp[cc + 3];
#pragma unroll
        for (int j = 0; j < 4; ++j) {
            acc[i][j][0] += q0; acc[i][j][1] += q1; acc[i][j][2] += q2; acc[i][j][3] += q3;
        }
    }
    // norms -> sg (wm deferred to epilogue)
    float sg[2][4]; int bmv[2][4];
#pragma unroll
    for (int h = 0; h < 2; ++h) {
        int e = wave * 2 + h;
#pragma unroll
        for (int j = 0; j < 4; ++j) {
            float nr = 0.f;
#pragma unroll
            for (int i2 = 0; i2 < 2; ++i2) {
                int i = h * 2 + i2;
#pragma unroll
                for (int r = 0; r < 4; ++r) nr += acc[i][j][r] * acc[i][j][r];
            }
            nr += __shfl_xor(nr, 16);
            nr += __shfl_xor(nr, 32);   // full 32-d norm on all rg lanes
            size_t o = ((size_t)(b * 8 + e)) * NPIX + n0 + j * 16 + l15;
            float z = zsg[o];
            int bm = idxg[o];
            float inv = 1.f / fmaxf(sqrtf(nr), 1e-12f);
            float s = 1.f / (1.f + __expf(-(beta + z * inv)));
            sg[h][j] = s; bmv[h][j] = bm;
            if (rg == 0) zsg[o] = s;    // sg out, in-place
        }
    }

    // ================= Phase g=1: value =================
    f32x4 acc2[4][4] = {};
#pragma unroll
    for (int kk = 0; kk < 8; ++kk) {
        const ushort* aCh = wb + (size_t)((8 + kk) * 4 + wave) * 2048;
        int k0 = kk * 32;
        bf16x8 af[4], bb[4];
#pragma unroll
        for (int i = 0; i < 4; ++i)
            af[i] = *(const bf16x8*)(aCh + (i * 64 + lane) * 8);
#pragma unroll
        for (int j = 0; j < 4; ++j) {
            int n = j * 16 + l15;
            int cs = (k0 + g8) ^ ((n & 7) << 3);
            bb[j] = *(const bf16x8*)(lB + (size_t)n * 256 + cs);
        }
#pragma unroll
        for (int i = 0; i < 4; ++i)
#pragma unroll
            for (int j = 0; j < 4; ++j)
                acc2[i][j] = __builtin_amdgcn_mfma_f32_16x16x32_bf16(af[i], bb[j], acc2[i][j], 0, 0, 0);
    }
    // + value bias
#pragma unroll
    for (int i = 0; i < 4; ++i) {
        int cc = wave * 64 + i * 16 + rg * 4;
        float q0 = bvp[cc], q1 = bvp[cc + 1], q2 = bvp[cc + 2], q3 = bvp[cc + 3];
#pragma unroll
        for (int j = 0; j < 4; ++j) {
            acc2[i][j][0] += q0; acc2[i][j][1] += q1; acc2[i][j][2] += q2; acc2[i][j][3] += q3;
        }
    }
    // quadrant ids (epilogue-only liveness)
    int mq[4];
#pragma unroll
    for (int j = 0; j < 4; ++j) {
        int n = n0 + j * 16 + l15;
        int hh = n / HH, ww = n - hh * HH;
        mq[j] = ((hh >= 48) ? 2 : 0) + ((ww >= 48) ? 1 : 0);
    }
    // weighted partial sums -> per-block row [be][nt][132], float4 stores
#pragma unroll
    for (int h = 0; h < 2; ++h) {
        int e = wave * 2 + h;
        float* prow = partial2 + ((size_t)(b * 8 + e) * NT + nt) * 132;
        float wm[4][4];
#pragma unroll
        for (int j = 0; j < 4; ++j)
#pragma unroll
            for (int m = 0; m < 4; ++m)
                wm[j][m] = ((bmv[h][j] == m) ? sg[h][j] : 0.f) + ((mq[j] == m) ? (1.f / 2304.f) : 0.f);
#pragma unroll
        for (int m = 0; m < 4; ++m) {
            float s = 0.f;
#pragma unroll
            for (int j = 0; j < 4; ++j) s += (bmv[h][j] == m) ? sg[h][j] : 0.f;
            s += __shfl_xor(s, 1); s += __shfl_xor(s, 2);
            s += __shfl_xor(s, 4); s += __shfl_xor(s, 8);
            if (lane == 0) prow[128 + m] = s;
        }
#pragma unroll
        for (int i2 = 0; i2 < 2; ++i2) {
            int i = h * 2 + i2;
#pragma unroll
            for (int m = 0; m < 4; ++m) {
                float sv[4];
#pragma unroll
                for (int r = 0; r < 4; ++r) {
                    float s = wm[0][m] * acc2[i][0][r] + wm[1][m] * acc2[i][1][r]
                            + wm[2][m] * acc2[i][2][r] + wm[3][m] * acc2[i][3][r];
                    s += __shfl_xor(s, 1); s += __shfl_xor(s, 2);
                    s += __shfl_xor(s, 4); s += __shfl_xor(s, 8);
                    sv[r] = s;
                }
                if (l15 == 0) {
                    int d0 = i2 * 16 + rg * 4;
                    *(float4*)(prow + m * 32 + d0) = make_float4(sv[0], sv[1], sv[2], sv[3]);
                }
            }
        }
    }
}

// ---------------------------------------------------------------------------
// psum: grid (128 be). tot[be][t] = sum_nt partial2[be][nt][t], t<132.
// ---------------------------------------------------------------------------
__global__ __launch_bounds__(256) void psum_kernel(const float* __restrict__ partial2,
                                                   float* __restrict__ tot) {
    int be = blockIdx.x;
    int t = threadIdx.x;
    if (t >= 132) return;
    const float* p = partial2 + (size_t)be * NT * 132 + t;
    float s = 0.f;
#pragma unroll 16
    for (int k = 0; k < NT; ++k) s += p[(size_t)k * 132];
    tot[be * 132 + t] = s;
}

// ---------------------------------------------------------------------------
// agg_pa v5: grid (16 b). aggs from tot[be][132], PAb = bf16(Wp·agg).
// ---------------------------------------------------------------------------
__global__ __launch_bounds__(256) void agg_pa_kernel(const float* __restrict__ tot,
                                                     const float* __restrict__ Wp,
                                                     ushort* __restrict__ PAb) {
    __shared__ float aggs[8][4][32];
    __shared__ float tmp[136];
    int b = blockIdx.x;
    int t = threadIdx.x;
    for (int e = 0; e < 8; ++e) {
        int be = b * 8 + e;
        if (t < 132) tmp[t] = tot[be * 132 + t];
        __syncthreads();
        if (t < 128) aggs[e][t >> 5][t & 31] = tmp[t] / (tmp[128 + (t >> 5)] + 1.0f);
        __syncthreads();
    }
    const float* wrow = Wp + (size_t)t * 256;
    unsigned u[16];
#pragma unroll
    for (int k = 0; k < 16; ++k) {
        float s0 = 0.f, s1 = 0.f;
        int em0 = 2 * k, em1 = 2 * k + 1;
        int e0 = em0 >> 2, m0 = em0 & 3;
        int e1 = em1 >> 2, m1 = em1 & 3;
#pragma unroll
        for (int d = 0; d < 32; ++d) {
            s0 += wrow[e0 * 32 + d] * aggs[e0][m0][d];
            s1 += wrow[e1 * 32 + d] * aggs[e1][m1][d];
        }
        u[k] = (unsigned)f2b(s0) | ((unsigned)f2b(s1) << 16);
    }
    uint4* pab = (uint4*)(PAb + (size_t)b * 8192 + (size_t)t * 32);
    pab[0] = make_uint4(u[0], u[1], u[2], u[3]);
    pab[1] = make_uint4(u[4], u[5], u[6], u[7]);
    pab[2] = make_uint4(u[8], u[9], u[10], u[11]);
    pab[3] = make_uint4(u[12], u[13], u[14], u[15]);
}

// ---------------------------------------------------------------------------
// gemm_out: out[b][o][n] = bp[o] + PA(256x32)·W(32xn); W built in registers.
// ---------------------------------------------------------------------------
__global__ __launch_bounds__(256) void gemm_out(const ushort* __restrict__ PAb,
                                                const float* __restrict__ sgv,
                                                const unsigned char* __restrict__ idxg,
                                                const float* __restrict__ bpp,
                                                float* __restrict__ out) {
    int nt = blockIdx.x, b = blockIdx.y;
    int t = threadIdx.x, wave = t >> 6, lane = t & 63;
    int wr = wave >> 1, wc = wave & 1;
    int l15 = lane & 15, kg = lane >> 4;
    const ushort* pab = PAb + (size_t)b * 8192;
    bf16x8 af[8];
#pragma unroll
    for (int i = 0; i < 8; ++i)
        af[i] = *(const bf16x8*)(pab + (size_t)(wr * 128 + i * 16 + l15) * 32 + kg * 8);
    int e0 = kg * 2;
    bf16x8 bb[4];
#pragma unroll
    for (int j = 0; j < 4; ++j) {
        int gn = nt * 128 + wc * 64 + j * 16 + l15;
        size_t ofs0 = ((size_t)(b * 8 + e0)) * NPIX + gn;
        float s0 = sgv[ofs0];
        float s1 = sgv[ofs0 + NPIX];
        int i0 = idxg[ofs0];
        int i1 = idxg[ofs0 + NPIX];
        unsigned h0 = f2b(s0), h1 = f2b(s1);
        unsigned w0 = (i0 & 1) ? (h0 << 16) : h0;
        unsigned w1 = (i1 & 1) ? (h1 << 16) : h1;
        uint4 q;
        q.x = (i0 >> 1) ? 0u : w0;
        q.y = (i0 >> 1) ? w0 : 0u;
        q.z = (i1 >> 1) ? 0u : w1;
        q.w = (i1 >> 1) ? w1 : 0u;
        bb[j] = __builtin_bit_cast(bf16x8, q);
    }
    f32x4 acc[8][4] = {};
#pragma unroll
    for (int i = 0; i < 8; ++i)
#pragma unroll
        for (int j = 0; j < 4; ++j)
            acc[i][j] = __builtin_amdgcn_mfma_f32_16x16x32_bf16(af[i], bb[j], acc[i][j], 0, 0, 0);
#pragma unroll
    for (int i = 0; i < 8; ++i) {
        int o0 = wr * 128 + i * 16 + kg * 4;
        float4 bi = *(const float4*)(bpp + o0);
#pragma unroll
        for (int j = 0; j < 4; ++j) {
            int gn = nt * 128 + wc * 64 + j * 16 + l15;
            size_t base = ((size_t)(b * 256 + o0)) * NPIX + gn;
            out[base] = acc[i][j][0] + bi.x;
            out[base + (size_t)NPIX] = acc[i][j][1] + bi.y;
            out[base + 2 * (size_t)NPIX] = acc[i][j][2] + bi.z;
            out[base + 3 * (size_t)NPIX] = acc[i][j][3] + bi.w;
        }
    }
}

// ---------------------------------------------------------------------------
extern "C" void kernel_launch(void* const* d_in, const int* in_sizes, int n_in,
                              void* d_out, int out_size, void* d_ws, size_t ws_size,
                              hipStream_t stream) {
    const float* x   = (const float*)d_in[0];
    const float* Wf  = (const float*)d_in[1];
    const float* bfp = (const float*)d_in[2];
    const float* Wv  = (const float*)d_in[3];
    const float* bvp = (const float*)d_in[4];
    const float* Wp  = (const float*)d_in[5];
    const float* bpp = (const float*)d_in[6];
    const float* al  = (const float*)d_in[7];
    const float* bt  = (const float*)d_in[8];
    const float* ce  = (const float*)d_in[9];
    float* out = (float*)d_out;

    // Workspace (bytes):
    char* ws = (char*)d_ws;
    float*  partial2 = (float*)ws;                               //  9,732,096 B ([be][nt][132])
    ushort* wbuf = (ushort*)(ws + 75497472);                     //    262,144 B (fragment-ordered)
    float*  GT   = (float*)(ws + 75759616);                      //     32,768 B
    float*  gb   = (float*)(ws + 75792384);                      //        256 B
    unsigned char* idxg = (unsigned char*)(ws + 75792640);       //  1,179,648 B
    float*  zbest = (float*)(ws + 76972288);                     //  4,718,592 B (->sg in-place)
    float*  tot   = (float*)(ws + 81690880);                     //     67,584 B
    ushort* PAb   = (ushort*)(ws + 82317568);                    //    262,144 B

    float* mapo = out + (size_t)BB * DD * NPIX;

    wprep_kernel<<<dim3(160), 256, 0, stream>>>(Wf, Wv, bfp, ce, wbuf, GT, gb);
    gmap_kernel<<<dim3(NT, BB), 256, 0, stream>>>(x, GT, gb, al, idxg, zbest, mapo);
    gemm_fvc<<<dim3(NT, BB), 256, 0, stream>>>(wbuf, bfp, bvp, x, idxg, zbest, bt, partial2);
    psum_kernel<<<dim3(128), 256, 0, stream>>>(partial2, tot);
    agg_pa_kernel<<<dim3(BB), 256, 0, stream>>>(tot, Wp, PAb);
    gemm_out<<<dim3(72, BB), 256, 0, stream>>>(PAb, zbest, idxg, bpp, out);
}

// Round 32
// 176.043 us; speedup vs baseline: 1.2948x; 1.2948x over previous
//
#include <hip/hip_runtime.h>
#include <hip/hip_bf16.h>

#define BB 16
#define CIN 256
#define DD 256
#define HH 96
#define NPIX 9216
#define HEADS 8
#define HD 32
#define MM 4
#define NT 144

typedef short bf16x8 __attribute__((ext_vector_type(8)));
typedef float f32x4 __attribute__((ext_vector_type(4)));

__device__ __forceinline__ float b2f(unsigned u) {
    unsigned x = u << 16;
    return __builtin_bit_cast(float, x);
}
__device__ __forceinline__ ushort f2b(float f) {
    unsigned x = __builtin_bit_cast(unsigned, f);
    unsigned r = (x + 0x7FFF + ((x >> 16) & 1)) >> 16;  // RNE
    return (ushort)r;
}
__device__ __forceinline__ unsigned cvtpk(float lo, float hi) {
    unsigned r;
    asm("v_cvt_pk_bf16_f32 %0, %1, %2" : "=v"(r) : "v"(lo), "v"(hi));
    return r;   // {bf16(hi)<<16 | bf16(lo)}, RNE — bit-identical to f2b pair
}

// ---------------------------------------------------------------------------
// wprep: blocks 0..127: Wf,Wv f32 -> bf16 wb in MFMA-FRAGMENT layout:
//   chunk (g*8+kk)*4+w (2048 ushorts): [(i*64+lane)*8+j] =
//   bf16(W_g[(w*64+i*16+(lane&15))*256 + kk*32+(lane>>4)*8+j])
// blocks 128..159: GT + gb (unchanged).
// ---------------------------------------------------------------------------
__global__ __launch_bounds__(256) void wprep_kernel(const float* __restrict__ Wf,
                                                    const float* __restrict__ Wv,
                                                    const float* __restrict__ bfp,
                                                    const float* __restrict__ centers,
                                                    ushort* __restrict__ wb,
                                                    float* __restrict__ GT,
                                                    float* __restrict__ gb) {
    __shared__ float cns[4][32];
    int t = threadIdx.x;
    if (blockIdx.x < 128) {
        int idx = (blockIdx.x * 256 + t) * 4;     // linear (g, rr, k0)
        float4 v;
        if (idx < 65536) v = *(const float4*)(Wf + idx);
        else v = *(const float4*)(Wv + (idx - 65536));
        int g = idx >> 16;
        int rem = idx & 65535;
        int rr = rem >> 8, k0 = rem & 255;
        int w = rr >> 6, i = (rr >> 4) & 3, l15v = rr & 15;
        int kk = k0 >> 5, lane4 = ((k0 >> 3) & 3) * 16 + l15v, j = k0 & 7;
        size_t dst = ((size_t)((g * 8 + kk) * 4 + w)) * 2048 + (i * 64 + lane4) * 8 + j;
        ushort4 o;
        o.x = f2b(v.x); o.y = f2b(v.y); o.z = f2b(v.z); o.w = f2b(v.w);
        *(ushort4*)(wb + dst) = o;
        return;
    }
    if (t < 4) {
        float c[32]; float s = 0.f;
        for (int d = 0; d < 32; ++d) { c[d] = centers[t * 32 + d]; s += c[d] * c[d]; }
        float inv = 1.f / fmaxf(sqrtf(s), 1e-12f);
        for (int d = 0; d < 32; ++d) cns[t][d] = c[d] * inv;
    }
    __syncthreads();
    int i = (blockIdx.x - 128) * 256 + t;
    int c = i >> 5, em = i & 31;
    int e = em >> 2, m = em & 3;
    float s = 0.f;
#pragma unroll 8
    for (int d = 0; d < 32; ++d) s += cns[m][d] * Wf[(e * 32 + d) * 256 + c];
    GT[i] = s;
    if (blockIdx.x == 128 && t < 32) {
        int e2 = t >> 2, m2 = t & 3;
        float sb = 0.f;
        for (int d = 0; d < 32; ++d) sb += cns[m2][d] * bfp[e2 * 32 + d];
        gb[t] = sb;
    }
}

// ---------------------------------------------------------------------------
// gmap v5 + mapo: em split by blockIdx.z. Grid (36,16,2).
// ---------------------------------------------------------------------------
__global__ __launch_bounds__(256) void gmap_kernel(const float* __restrict__ x,
                                                   const float* __restrict__ GT,
                                                   const float* __restrict__ gb,
                                                   const float* __restrict__ alpha_p,
                                                   unsigned char* __restrict__ idxg,
                                                   float* __restrict__ zbest,
                                                   float* __restrict__ mapo) {
    int b = blockIdx.y;
    int emh = blockIdx.z;                    // 0: em 0..15 (heads 0-3), 1: em 16..31
    int t = threadIdx.x;
    int n = blockIdx.x * 256 + t;
    float acc[16];
#pragma unroll
    for (int em = 0; em < 16; ++em) acc[em] = gb[emh * 16 + em];
    const float* xb = x + (size_t)b * CIN * NPIX + n;
    const float* gtb = GT + emh * 16;
#pragma unroll 8
    for (int c = 0; c < 256; ++c) {
        float xv = xb[(size_t)c * NPIX];
        const float* gr = gtb + c * 32;      // blockIdx-uniform -> s_load
#pragma unroll
        for (int em = 0; em < 16; ++em) acc[em] = fmaf(gr[em], xv, acc[em]);
    }
    float alpha = alpha_p[0];
#pragma unroll
    for (int h = 0; h < 4; ++h) {
        int e = emh * 4 + h;
        float z0 = alpha * acc[h * 4 + 0], z1 = alpha * acc[h * 4 + 1];
        float z2 = alpha * acc[h * 4 + 2], z3 = alpha * acc[h * 4 + 3];
        int bm = 0; float bz = z0;
        if (z1 > bz) { bz = z1; bm = 1; }
        if (z2 > bz) { bz = z2; bm = 2; }
        if (z3 > bz) { bz = z3; bm = 3; }
        size_t o = ((size_t)(b * 8 + e)) * NPIX + n;
        idxg[o] = (unsigned char)bm;
        zbest[o] = bz;
        if (b == 0 && emh == 0 && h == 0) mapo[n] = (float)bm;
    }
}

// ---------------------------------------------------------------------------
// gemm_fvc v10: fragment-direct A loads + deferred wm (r30, verified best).
// Grid (144,16).
// ---------------------------------------------------------------------------
__global__ __launch_bounds__(256, 3) void gemm_fvc(const ushort* __restrict__ wb,
                                                   const float* __restrict__ bfp,
                                                   const float* __restrict__ bvp,
                                                   const float* __restrict__ x,
                                                   const unsigned char* __restrict__ idxg,
                                                   float* __restrict__ zsg,
                                                   const float* __restrict__ beta_p,
                                                   float* __restrict__ partial2) {
    __shared__ ushort lB[64 * 256];       // 32 KB, swizzled
    int nt = blockIdx.x, b = blockIdx.y;
    int t = threadIdx.x;
    int wave = t >> 6, lane = t & 63;
    int l15 = lane & 15, g8 = (lane >> 4) * 8, rg = lane >> 4;
    int n0 = nt * 64;

    // ---- B-stage: thread t: c-pairs c0 = s*64 + 2*(t&31), n-block (t>>5)*8
    {
        int cpl = 2 * (t & 31);
        int j0 = (t >> 5) * 8;
#pragma unroll
        for (int s = 0; s < 4; ++s) {
            int c0 = s * 64 + cpl;
            const float* xr = x + ((size_t)(b * CIN + c0)) * NPIX + n0 + j0;
            float4 u0 = *(const float4*)(xr);
            float4 u1 = *(const float4*)(xr + 4);
            float4 v0 = *(const float4*)(xr + NPIX);
            float4 v1 = *(const float4*)(xr + NPIX + 4);
            float a0[8] = {u0.x, u0.y, u0.z, u0.w, u1.x, u1.y, u1.z, u1.w};
            float a1[8] = {v0.x, v0.y, v0.z, v0.w, v1.x, v1.y, v1.z, v1.w};
#pragma unroll
            for (int i = 0; i < 8; ++i) {
                int n = j0 + i;
                int cs = c0 ^ ((n & 7) << 3);
                unsigned pk = cvtpk(a0[i], a1[i]);   // RNE, = f2b pair
                *(unsigned*)(lB + (size_t)n * 256 + cs) = pk;
            }
        }
    }

    float beta = beta_p[0];

    __syncthreads();   // lB ready (single barrier)

    // ================= Phase g=0: feat =================
    f32x4 acc[4][4] = {};
#pragma unroll
    for (int kk = 0; kk < 8; ++kk) {
        const ushort* aCh = wb + (size_t)(kk * 4 + wave) * 2048;
        int k0 = kk * 32;
        bf16x8 af[4], bb[4];
#pragma unroll
        for (int i = 0; i < 4; ++i)
            af[i] = *(const bf16x8*)(aCh + (i * 64 + lane) * 8);   // coalesced, L2-hot
#pragma unroll
        for (int j = 0; j < 4; ++j) {
            int n = j * 16 + l15;
            int cs = (k0 + g8) ^ ((n & 7) << 3);
            bb[j] = *(const bf16x8*)(lB + (size_t)n * 256 + cs);
        }
#pragma unroll
        for (int i = 0; i < 4; ++i)
#pragma unroll
            for (int j = 0; j < 4; ++j)
                acc[i][j] = __builtin_amdgcn_mfma_f32_16x16x32_bf16(af[i], bb[j], acc[i][j], 0, 0, 0);
    }
    // + feat bias (f32, unrounded)
#pragma unroll
    for (int i = 0; i < 4; ++i) {
        int cc = wave * 64 + i * 16 + rg * 4;
        float q0 = bfp[cc], q1 = bfp[cc + 1], q2 = bfp[cc + 2], q3 = bfp[cc + 3];
#pragma unroll
        for (int j = 0; j < 4; ++j) {
            acc[i][j][0] += q0; acc[i][j][1] += q1; acc[i][j][2] += q2; acc[i][j][3] += q3;
        }
    }
    // norms -> sg (wm deferred to epilogue)
    float sg[2][4]; int bmv[2][4];
#pragma unroll
    for (int h = 0; h < 2; ++h) {
        int e = wave * 2 + h;
#pragma unroll
        for (int j = 0; j < 4; ++j) {
            float nr = 0.f;
#pragma unroll
            for (int i2 = 0; i2 < 2; ++i2) {
                int i = h * 2 + i2;
#pragma unroll
                for (int r = 0; r < 4; ++r) nr += acc[i][j][r] * acc[i][j][r];
            }
            nr += __shfl_xor(nr, 16);
            nr += __shfl_xor(nr, 32);   // full 32-d norm on all rg lanes
            size_t o = ((size_t)(b * 8 + e)) * NPIX + n0 + j * 16 + l15;
            float z = zsg[o];
            int bm = idxg[o];
            float inv = 1.f / fmaxf(sqrtf(nr), 1e-12f);
            float s = 1.f / (1.f + __expf(-(beta + z * inv)));
            sg[h][j] = s; bmv[h][j] = bm;
            if (rg == 0) zsg[o] = s;    // sg out, in-place
        }
    }

    // ================= Phase g=1: value =================
    f32x4 acc2[4][4] = {};
#pragma unroll
    for (int kk = 0; kk < 8; ++kk) {
        const ushort* aCh = wb + (size_t)((8 + kk) * 4 + wave) * 2048;
        int k0 = kk * 32;
        bf16x8 af[4], bb[4];
#pragma unroll
        for (int i = 0; i < 4; ++i)
            af[i] = *(const bf16x8*)(aCh + (i * 64 + lane) * 8);
#pragma unroll
        for (int j = 0; j < 4; ++j) {
            int n = j * 16 + l15;
            int cs = (k0 + g8) ^ ((n & 7) << 3);
            bb[j] = *(const bf16x8*)(lB + (size_t)n * 256 + cs);
        }
#pragma unroll
        for (int i = 0; i < 4; ++i)
#pragma unroll
            for (int j = 0; j < 4; ++j)
                acc2[i][j] = __builtin_amdgcn_mfma_f32_16x16x32_bf16(af[i], bb[j], acc2[i][j], 0, 0, 0);
    }
    // + value bias
#pragma unroll
    for (int i = 0; i < 4; ++i) {
        int cc = wave * 64 + i * 16 + rg * 4;
        float q0 = bvp[cc], q1 = bvp[cc + 1], q2 = bvp[cc + 2], q3 = bvp[cc + 3];
#pragma unroll
        for (int j = 0; j < 4; ++j) {
            acc2[i][j][0] += q0; acc2[i][j][1] += q1; acc2[i][j][2] += q2; acc2[i][j][3] += q3;
        }
    }
    // quadrant ids (epilogue-only liveness)
    int mq[4];
#pragma unroll
    for (int j = 0; j < 4; ++j) {
        int n = n0 + j * 16 + l15;
        int hh = n / HH, ww = n - hh * HH;
        mq[j] = ((hh >= 48) ? 2 : 0) + ((ww >= 48) ? 1 : 0);
    }
    // weighted partial sums -> per-block row [be][nt][132], float4 stores
#pragma unroll
    for (int h = 0; h < 2; ++h) {
        int e = wave * 2 + h;
        float* prow = partial2 + ((size_t)(b * 8 + e) * NT + nt) * 132;
        float wm[4][4];
#pragma unroll
        for (int j = 0; j < 4; ++j)
#pragma unroll
            for (int m = 0; m < 4; ++m)
                wm[j][m] = ((bmv[h][j] == m) ? sg[h][j] : 0.f) + ((mq[j] == m) ? (1.f / 2304.f) : 0.f);
#pragma unroll
        for (int m = 0; m < 4; ++m) {
            float s = 0.f;
#pragma unroll
            for (int j = 0; j < 4; ++j) s += (bmv[h][j] == m) ? sg[h][j] : 0.f;
            s += __shfl_xor(s, 1); s += __shfl_xor(s, 2);
            s += __shfl_xor(s, 4); s += __shfl_xor(s, 8);
            if (lane == 0) prow[128 + m] = s;
        }
#pragma unroll
        for (int i2 = 0; i2 < 2; ++i2) {
            int i = h * 2 + i2;
#pragma unroll
            for (int m = 0; m < 4; ++m) {
                float sv[4];
#pragma unroll
                for (int r = 0; r < 4; ++r) {
                    float s = wm[0][m] * acc2[i][0][r] + wm[1][m] * acc2[i][1][r]
                            + wm[2][m] * acc2[i][2][r] + wm[3][m] * acc2[i][3][r];
                    s += __shfl_xor(s, 1); s += __shfl_xor(s, 2);
                    s += __shfl_xor(s, 4); s += __shfl_xor(s, 8);
                    sv[r] = s;
                }
                if (l15 == 0) {
                    int d0 = i2 * 16 + rg * 4;
                    *(float4*)(prow + m * 32 + d0) = make_float4(sv[0], sv[1], sv[2], sv[3]);
                }
            }
        }
    }
}

// ---------------------------------------------------------------------------
// psum: grid (128 be). tot[be][t] = sum_nt partial2[be][nt][t], t<132.
// ---------------------------------------------------------------------------
__global__ __launch_bounds__(256) void psum_kernel(const float* __restrict__ partial2,
                                                   float* __restrict__ tot) {
    int be = blockIdx.x;
    int t = threadIdx.x;
    if (t >= 132) return;
    const float* p = partial2 + (size_t)be * NT * 132 + t;
    float s = 0.f;
#pragma unroll 16
    for (int k = 0; k < NT; ++k) s += p[(size_t)k * 132];
    tot[be * 132 + t] = s;
}

// ---------------------------------------------------------------------------
// agg_pa v5: grid (16 b). aggs from tot[be][132], PAb = bf16(Wp·agg).
// ---------------------------------------------------------------------------
__global__ __launch_bounds__(256) void agg_pa_kernel(const float* __restrict__ tot,
                                                     const float* __restrict__ Wp,
                                                     ushort* __restrict__ PAb) {
    __shared__ float aggs[8][4][32];
    __shared__ float tmp[136];
    int b = blockIdx.x;
    int t = threadIdx.x;
    for (int e = 0; e < 8; ++e) {
        int be = b * 8 + e;
        if (t < 132) tmp[t] = tot[be * 132 + t];
        __syncthreads();
        if (t < 128) aggs[e][t >> 5][t & 31] = tmp[t] / (tmp[128 + (t >> 5)] + 1.0f);
        __syncthreads();
    }
    const float* wrow = Wp + (size_t)t * 256;
    unsigned u[16];
#pragma unroll
    for (int k = 0; k < 16; ++k) {
        float s0 = 0.f, s1 = 0.f;
        int em0 = 2 * k, em1 = 2 * k + 1;
        int e0 = em0 >> 2, m0 = em0 & 3;
        int e1 = em1 >> 2, m1 = em1 & 3;
#pragma unroll
        for (int d = 0; d < 32; ++d) {
            s0 += wrow[e0 * 32 + d] * aggs[e0][m0][d];
            s1 += wrow[e1 * 32 + d] * aggs[e1][m1][d];
        }
        u[k] = (unsigned)f2b(s0) | ((unsigned)f2b(s1) << 16);
    }
    uint4* pab = (uint4*)(PAb + (size_t)b * 8192 + (size_t)t * 32);
    pab[0] = make_uint4(u[0], u[1], u[2], u[3]);
    pab[1] = make_uint4(u[4], u[5], u[6], u[7]);
    pab[2] = make_uint4(u[8], u[9], u[10], u[11]);
    pab[3] = make_uint4(u[12], u[13], u[14], u[15]);
}

// ---------------------------------------------------------------------------
// gemm_out: out[b][o][n] = bp[o] + PA(256x32)·W(32xn); W built in registers.
// ---------------------------------------------------------------------------
__global__ __launch_bounds__(256) void gemm_out(const ushort* __restrict__ PAb,
                                                const float* __restrict__ sgv,
                                                const unsigned char* __restrict__ idxg,
                                                const float* __restrict__ bpp,
                                                float* __restrict__ out) {
    int nt = blockIdx.x, b = blockIdx.y;
    int t = threadIdx.x, wave = t >> 6, lane = t & 63;
    int wr = wave >> 1, wc = wave & 1;
    int l15 = lane & 15, kg = lane >> 4;
    const ushort* pab = PAb + (size_t)b * 8192;
    bf16x8 af[8];
#pragma unroll
    for (int i = 0; i < 8; ++i)
        af[i] = *(const bf16x8*)(pab + (size_t)(wr * 128 + i * 16 + l15) * 32 + kg * 8);
    int e0 = kg * 2;
    bf16x8 bb[4];
#pragma unroll
    for (int j = 0; j < 4; ++j) {
        int gn = nt * 128 + wc * 64 + j * 16 + l15;
        size_t ofs0 = ((size_t)(b * 8 + e0)) * NPIX + gn;
        float s0 = sgv[ofs0];
        float s1 = sgv[ofs0 + NPIX];
        int i0 = idxg[ofs0];
        int i1 = idxg[ofs0 + NPIX];
        unsigned h0 = f2b(s0), h1 = f2b(s1);
        unsigned w0 = (i0 & 1) ? (h0 << 16) : h0;
        unsigned w1 = (i1 & 1) ? (h1 << 16) : h1;
        uint4 q;
        q.x = (i0 >> 1) ? 0u : w0;
        q.y = (i0 >> 1) ? w0 : 0u;
        q.z = (i1 >> 1) ? 0u : w1;
        q.w = (i1 >> 1) ? w1 : 0u;
        bb[j] = __builtin_bit_cast(bf16x8, q);
    }
    f32x4 acc[8][4] = {};
#pragma unroll
    for (int i = 0; i < 8; ++i)
#pragma unroll
        for (int j = 0; j < 4; ++j)
            acc[i][j] = __builtin_amdgcn_mfma_f32_16x16x32_bf16(af[i], bb[j], acc[i][j], 0, 0, 0);
#pragma unroll
    for (int i = 0; i < 8; ++i) {
        int o0 = wr * 128 + i * 16 + kg * 4;
        float4 bi = *(const float4*)(bpp + o0);
#pragma unroll
        for (int j = 0; j < 4; ++j) {
            int gn = nt * 128 + wc * 64 + j * 16 + l15;
            size_t base = ((size_t)(b * 256 + o0)) * NPIX + gn;
            out[base] = acc[i][j][0] + bi.x;
            out[base + (size_t)NPIX] = acc[i][j][1] + bi.y;
            out[base + 2 * (size_t)NPIX] = acc[i][j][2] + bi.z;
            out[base + 3 * (size_t)NPIX] = acc[i][j][3] + bi.w;
        }
    }
}

// ---------------------------------------------------------------------------
extern "C" void kernel_launch(void* const* d_in, const int* in_sizes, int n_in,
                              void* d_out, int out_size, void* d_ws, size_t ws_size,
                              hipStream_t stream) {
    const float* x   = (const float*)d_in[0];
    const float* Wf  = (const float*)d_in[1];
    const float* bfp = (const float*)d_in[2];
    const float* Wv  = (const float*)d_in[3];
    const float* bvp = (const float*)d_in[4];
    const float* Wp  = (const float*)d_in[5];
    const float* bpp = (const float*)d_in[6];
    const float* al  = (const float*)d_in[7];
    const float* bt  = (const float*)d_in[8];
    const float* ce  = (const float*)d_in[9];
    float* out = (float*)d_out;

    // Workspace (bytes):
    char* ws = (char*)d_ws;
    float*  partial2 = (float*)ws;                               //  9,732,096 B ([be][nt][132])
    ushort* wbuf = (ushort*)(ws + 75497472);                     //    262,144 B (fragment-ordered)
    float*  GT   = (float*)(ws + 75759616);                      //     32,768 B
    float*  gb   = (float*)(ws + 75792384);                      //        256 B
    unsigned char* idxg = (unsigned char*)(ws + 75792640);       //  1,179,648 B
    float*  zbest = (float*)(ws + 76972288);                     //  4,718,592 B (->sg in-place)
    float*  tot   = (float*)(ws + 81690880);                     //     67,584 B
    ushort* PAb   = (ushort*)(ws + 82317568);                    //    262,144 B

    float* mapo = out + (size_t)BB * DD * NPIX;

    wprep_kernel<<<dim3(160), 256, 0, stream>>>(Wf, Wv, bfp, ce, wbuf, GT, gb);
    gmap_kernel<<<dim3(36, BB, 2), 256, 0, stream>>>(x, GT, gb, al, idxg, zbest, mapo);
    gemm_fvc<<<dim3(NT, BB), 256, 0, stream>>>(wbuf, bfp, bvp, x, idxg, zbest, bt, partial2);
    psum_kernel<<<dim3(128), 256, 0, stream>>>(partial2, tot);
    agg_pa_kernel<<<dim3(BB), 256, 0, stream>>>(tot, Wp, PAb);
    gemm_out<<<dim3(72, BB), 256, 0, stream>>>(PAb, zbest, idxg, bpp, out);
}